// Round 7
// baseline (332.104 us; speedup 1.0000x reference)
//
#include <hip/hip_runtime.h>

// CustomRNN: B=2048, T=512, I=1, H=64.
// Round-7: register-resident recurrence (round-6 structure, verified
// absmax 9.8e-4) + occupancy/issue fixes:
//  * 512-thread blocks = 8 independent waves (no barriers) -> 2 waves/SIMD,
//    HW round-robin fills the ~650 cyc/step stall measured in round 6.
//  * W-lo correction dropped (8 MFMA + 16 fma/step saved): W_hh plain fp16,
//    est. absmax ~2-4e-3 vs 7.9e-3 threshold.
//  * x: depth-2 float4 register prefetch from global (L2-resident), no LDS.
//  * c-setup as v_pk_fma_f32; fc epilogue reads final fp16 h from bh regs.
// Row map (verified r6): tile m, within-tile row c ->
//   r = 8*(c>>2)+(c&3)+4*(m&1)+32*(m>>1); then lane (q,col)'s D rows are
//   exactly its next-step B-fragment B[k=8q+j][n=col] -> h never leaves regs.

typedef _Float16 v8h __attribute__((ext_vector_type(8)));
typedef float    v2f __attribute__((ext_vector_type(2)));
typedef float    v4f __attribute__((ext_vector_type(4)));
typedef int      v4i __attribute__((ext_vector_type(4)));

__global__ __launch_bounds__(512, 2)
void rnn_reg(
    const float* __restrict__ x,      // [B, T]
    const float* __restrict__ W_ih,   // [64, 1]
    const float* __restrict__ W_hh,   // [64, 64]
    const float* __restrict__ b_ih,   // [64]
    const float* __restrict__ b_hh,   // [64]
    const float* __restrict__ fc_w,   // [1, 64]
    const float* __restrict__ fc_b,   // [1]
    float* __restrict__ out,          // [B, 1]
    int B, int T)
{
    const int lane = threadIdx.x & 63;
    const int wv   = threadIdx.x >> 6;          // 0..7, independent waves
    const int q    = lane >> 4;
    const int col  = lane & 15;
    const int tile   = blockIdx.x * 8 + wv;     // 16-batch tile id
    const int batch0 = tile * 16;
    if (batch0 >= B) return;                    // no barriers anywhere: safe

    const int  gb    = batch0 + col;
    const bool valid = gb < B;
    const float* xp  = x + (size_t)(valid ? gb : 0) * T;

    // ---- A fragments: lane (q,col) holds A[c=col][k=8q+j] of tile m ----
    v8h Ah[4][2];
#pragma unroll
    for (int m = 0; m < 4; ++m) {
        const int r = 8 * (col >> 2) + (col & 3) + 4 * (m & 1) + 32 * (m >> 1);
        const float* wrow = W_hh + (size_t)r * 64;
#pragma unroll
        for (int kt = 0; kt < 2; ++kt) {
            const float4 w0 = *(const float4*)(wrow + kt * 32 + 8 * q);
            const float4 w1 = *(const float4*)(wrow + kt * 32 + 8 * q + 4);
            const float wf[8] = {w0.x, w0.y, w0.z, w0.w, w1.x, w1.y, w1.z, w1.w};
#pragma unroll
            for (int j = 0; j < 8; ++j) Ah[m][kt][j] = (_Float16)wf[j];
        }
    }
    // per-lane D-row constants, packed in pairs: rows r(m, 2*p2+e) =
    // 8q + 2*p2 + e + 4*(m&1) + 32*(m>>1)
    v2f bias2[4][2], wih2[4][2];
#pragma unroll
    for (int m = 0; m < 4; ++m)
#pragma unroll
        for (int p2 = 0; p2 < 2; ++p2) {
            const int r0 = 8 * q + 2 * p2 + 4 * (m & 1) + 32 * (m >> 1);
            bias2[m][p2] = (v2f){ b_ih[r0] + b_hh[r0], b_ih[r0 + 1] + b_hh[r0 + 1] };
            wih2[m][p2]  = (v2f){ W_ih[r0], W_ih[r0 + 1] };
        }

    // ---- register-resident recurrence ----
    v8h bh0 = {}, bh1 = {};   // h fragments: k=8q+j and k=32+8q+j

    auto step = [&](float xv) {
        const v2f xv2 = { xv, xv };
        v4f acc[4];
#pragma unroll
        for (int m = 0; m < 4; ++m) {
            const v2f c0 = __builtin_elementwise_fma(xv2, wih2[m][0], bias2[m][0]);
            const v2f c1 = __builtin_elementwise_fma(xv2, wih2[m][1], bias2[m][1]);
            const v4f c  = { c0.x, c0.y, c1.x, c1.y };
            acc[m] = __builtin_amdgcn_mfma_f32_16x16x32_f16(Ah[m][0], bh0, c, 0, 0, 0);
            acc[m] = __builtin_amdgcn_mfma_f32_16x16x32_f16(Ah[m][1], bh1, acc[m], 0, 0, 0);
        }
        int pk[8];
#pragma unroll
        for (int m = 0; m < 4; ++m) {
#pragma unroll
            for (int h2 = 0; h2 < 2; ++h2) {
                const int i0 = 2 * h2;
                const v2f a2  = { acc[m][i0], acc[m][i0 + 1] };
                // tanh(a) = 1 - 2/(1 + exp(2a)); one rcp shared by the pair
                const v2f ein = a2 * 2.885390081777927f;          // 2a/ln2
                const v2f e   = { __builtin_amdgcn_exp2f(ein.x),
                                  __builtin_amdgcn_exp2f(ein.y) };
                const v2f u   = e + 1.0f;
                const float nr = -2.0f * __builtin_amdgcn_rcpf(u.x * u.y);
                const v2f us  = { u.y, u.x };
                const v2f nrv = { nr, nr };
                const v2f one = { 1.0f, 1.0f };
                const v2f t2  = __builtin_elementwise_fma(us, nrv, one);
                pk[m * 2 + h2] = __builtin_bit_cast(int,
                                     __builtin_amdgcn_cvt_pkrtz(t2.x, t2.y));
            }
        }
        const v4i lo = { pk[0], pk[1], pk[2], pk[3] };   // tiles 0,1 -> k 0..31
        const v4i hi = { pk[4], pk[5], pk[6], pk[7] };   // tiles 2,3 -> k 32..63
        bh0 = __builtin_bit_cast(v8h, lo);
        bh1 = __builtin_bit_cast(v8h, hi);
    };

    // ---- main loop: depth-2 float4 register prefetch of x ----
    const int TqF = T >> 2, tail = T & 3;
    float4 xq0 = make_float4(0.f, 0.f, 0.f, 0.f);
    float4 xq1 = xq0;
    if (valid) {
        if (T >= 4) xq0 = *(const float4*)(xp);
        if (T >= 8) xq1 = *(const float4*)(xp + 4);
    }
    for (int t4 = 0; t4 < TqF; ++t4) {
        float4 xq2 = make_float4(0.f, 0.f, 0.f, 0.f);
        const int nb = 4 * (t4 + 2);
        if (valid && nb + 4 <= T) xq2 = *(const float4*)(xp + nb);
        step(xq0.x); step(xq0.y); step(xq0.z); step(xq0.w);
        xq0 = xq1; xq1 = xq2;
    }
#pragma unroll 1
    for (int i = 0; i < tail; ++i)
        step(valid ? xp[4 * TqF + i] : 0.f);

    // ---- fc epilogue from final fp16 h in bh regs ----
    // bh0[j] = h[8q+j], bh1[j] = h[32+8q+j] for batch col
    float v = 0.f;
#pragma unroll
    for (int j = 0; j < 8; ++j) {
        v = __builtin_fmaf((float)bh0[j], fc_w[8 * q + j], v);
        v = __builtin_fmaf((float)bh1[j], fc_w[32 + 8 * q + j], v);
    }
    v += __shfl_xor(v, 16, 64);   // combine the 4 q-lanes of this col
    v += __shfl_xor(v, 32, 64);
    if (lane < 16 && batch0 + lane < B) out[batch0 + lane] = v + fc_b[0];
}

extern "C" void kernel_launch(void* const* d_in, const int* in_sizes, int n_in,
                              void* d_out, int out_size, void* d_ws, size_t ws_size,
                              hipStream_t stream) {
    const float* x    = (const float*)d_in[0];
    const float* W_ih = (const float*)d_in[1];
    const float* W_hh = (const float*)d_in[2];
    const float* b_ih = (const float*)d_in[3];
    const float* b_hh = (const float*)d_in[4];
    const float* fc_w = (const float*)d_in[5];
    const float* fc_b = (const float*)d_in[6];
    float* out = (float*)d_out;

    const int B = out_size;          // output is [B, 1]
    const int T = in_sizes[0] / B;   // I == 1

    const int blocks = (B + 127) / 128;   // 8 tiles of 16 batches per block
    rnn_reg<<<blocks, 512, 0, stream>>>(x, W_ih, W_hh, b_ih, b_hh,
                                        fc_w, fc_b, out, B, T);
}